// Round 1
// baseline (952.811 us; speedup 1.0000x reference)
//
#include <hip/hip_runtime.h>
#include <hip/hip_bf16.h>

#define NUM_STEPS 10
#define DT 0.1f

typedef __bf16 bf16_t;
typedef __bf16 bf16x8 __attribute__((ext_vector_type(8)));
typedef __bf16 bf16x4 __attribute__((ext_vector_type(4)));
typedef float f32x4 __attribute__((ext_vector_type(4)));

// async global->LDS, 16B per lane; LDS dst is wave-uniform base + lane*16
__device__ __forceinline__ void async16(const bf16_t* g, bf16_t* l) {
  __builtin_amdgcn_global_load_lds(
      (const __attribute__((address_space(1))) void*)g,
      (__attribute__((address_space(3))) void*)l, 16, 0, 0);
}

__global__ void cvt_f32_to_bf16(const float* __restrict__ in,
                                bf16_t* __restrict__ out, int n4) {
  int i = blockIdx.x * blockDim.x + threadIdx.x;
  if (i < n4) {
    float4 v = ((const float4*)in)[i];
    bf16x4 o = {(bf16_t)v.x, (bf16_t)v.y, (bf16_t)v.z, (bf16_t)v.w};
    ((bf16x4*)out)[i] = o;
  }
}

__global__ void init_h(const float* __restrict__ h0, float* __restrict__ hout,
                       bf16_t* __restrict__ hb, int n4) {
  int i = blockIdx.x * blockDim.x + threadIdx.x;
  if (i < n4) {
    float4 v = ((const float4*)h0)[i];
    ((float4*)hout)[i] = v;
    bf16x4 o = {(bf16_t)v.x, (bf16_t)v.y, (bf16_t)v.z, (bf16_t)v.w};
    ((bf16x4*)hb)[i] = o;
  }
}

// C[M,N] = A[M,K] * B[N,K]^T   (NT layout, both row-major, K contiguous)
// EPI=0: out_ihb = acc + bias1[col] + bias2[col]
// EPI=1: pre = acc + ihb; t=tanh(pre); d=exp(-DT/tau);
//        h_io = d*h_io + (1-d)*t;  hb_next = bf16(h_io)
template <int EPI>
__global__ __launch_bounds__(256, 2) void gemm_nt(
    const bf16_t* __restrict__ A, const bf16_t* __restrict__ Bw, int M, int N,
    int K, const float* __restrict__ bias1, const float* __restrict__ bias2,
    float* __restrict__ out_ihb, const float* __restrict__ ihb,
    const float* __restrict__ tau, float* __restrict__ h_io,
    bf16_t* __restrict__ hb_next) {
  __shared__ __align__(16) bf16_t As[128 * 32];
  __shared__ __align__(16) bf16_t Bs[128 * 32];
  const int tid = threadIdx.x;
  const int lane = tid & 63;
  const int wave = tid >> 6;
  const int waveM = wave >> 1, waveN = wave & 1;
  const long bRow = (long)blockIdx.y * 128;
  const long bCol = (long)blockIdx.x * 128;

  // staging: 8 wave-instructions cover 128 rows x 32 cols (bf16);
  // wave w, rep r covers rows (w*2+r)*16 .. +16; lane L -> row L/4, col chunk L%4
  const int sRow = lane >> 2;
  const int sCol = (lane & 3) << 3;
  const bf16_t* aG = A + (bRow + wave * 32 + sRow) * (long)K + sCol;
  const bf16_t* bG = Bw + (bCol + wave * 32 + sRow) * (long)K + sCol;
  bf16_t* aL0 = &As[(wave * 2 + 0) * 512];
  bf16_t* aL1 = &As[(wave * 2 + 1) * 512];
  bf16_t* bL0 = &Bs[(wave * 2 + 0) * 512];
  bf16_t* bL1 = &Bs[(wave * 2 + 1) * 512];

  // MFMA fragment addressing: operand[row = lane&15][k = (lane>>4)*8 + j]
  const int fRow = lane & 15;
  const int fK = (lane >> 4) << 3;

  f32x4 acc[4][4] = {};

  for (int k0 = 0; k0 < K; k0 += 32) {
    async16(aG + k0, aL0);
    async16(aG + 16 * (long)K + k0, aL1);
    async16(bG + k0, bL0);
    async16(bG + 16 * (long)K + k0, bL1);
    __syncthreads();  // compiler emits s_waitcnt vmcnt(0) before barrier

    bf16x8 aF[4], bF[4];
#pragma unroll
    for (int t = 0; t < 4; ++t) {
      aF[t] = *(const bf16x8*)&As[(waveM * 64 + t * 16 + fRow) * 32 + fK];
      bF[t] = *(const bf16x8*)&Bs[(waveN * 64 + t * 16 + fRow) * 32 + fK];
    }
#pragma unroll
    for (int mt = 0; mt < 4; ++mt)
#pragma unroll
      for (int nt = 0; nt < 4; ++nt)
        acc[mt][nt] = __builtin_amdgcn_mfma_f32_16x16x32_bf16(
            aF[mt], bF[nt], acc[mt][nt], 0, 0, 0);
    __syncthreads();
  }

  // C/D layout: col = lane&15, row = (lane>>4)*4 + reg   [measured m89/m91]
  const int eRow = (lane >> 4) << 2;
  const int eCol = lane & 15;

  if (EPI == 0) {
#pragma unroll
    for (int nt = 0; nt < 4; ++nt) {
      const int col = (int)bCol + waveN * 64 + nt * 16 + eCol;
      const float bb = bias1[col] + bias2[col];
#pragma unroll
      for (int mt = 0; mt < 4; ++mt) {
        const long row = bRow + waveM * 64 + mt * 16 + eRow;
#pragma unroll
        for (int r = 0; r < 4; ++r)
          out_ihb[(row + r) * N + col] = acc[mt][nt][r] + bb;
      }
    }
  } else {
#pragma unroll
    for (int nt = 0; nt < 4; ++nt) {
      const int col = (int)bCol + waveN * 64 + nt * 16 + eCol;
      const float dcy = __expf(-DT / tau[col]);
#pragma unroll
      for (int mt = 0; mt < 4; ++mt) {
        const long row = bRow + waveM * 64 + mt * 16 + eRow;
#pragma unroll
        for (int r = 0; r < 4; ++r) {
          const long idx = (row + r) * N + col;
          float pre = acc[mt][nt][r] + ihb[idx];
          float t = tanhf(pre);
          float hn = dcy * h_io[idx] + (1.0f - dcy) * t;
          h_io[idx] = hn;
          hb_next[idx] = (bf16_t)hn;
        }
      }
    }
  }
}

extern "C" void kernel_launch(void* const* d_in, const int* in_sizes, int n_in,
                              void* d_out, int out_size, void* d_ws,
                              size_t ws_size, hipStream_t stream) {
  const float* x = (const float*)d_in[0];
  const float* h0 = (const float*)d_in[1];
  const float* W_ih = (const float*)d_in[2];
  const float* b_ih = (const float*)d_in[3];
  const float* W_hh = (const float*)d_in[4];
  const float* b_hh = (const float*)d_in[5];
  const float* tau = (const float*)d_in[6];
  float* hout = (float*)d_out;

  const int B = 4096, I = 1024, H = 2048;

  char* ws = (char*)d_ws;
  float* ihb = (float*)ws;   ws += (size_t)B * H * 4;   // 32 MB
  bf16_t* hb0 = (bf16_t*)ws; ws += (size_t)B * H * 2;   // 16 MB
  bf16_t* hb1 = (bf16_t*)ws; ws += (size_t)B * H * 2;   // 16 MB
  bf16_t* xb = (bf16_t*)ws;  ws += (size_t)B * I * 2;   // 8 MB
  bf16_t* wihb = (bf16_t*)ws; ws += (size_t)H * I * 2;  // 4 MB
  bf16_t* whhb = (bf16_t*)ws; ws += (size_t)H * H * 2;  // 8 MB

  cvt_f32_to_bf16<<<(B * I / 4 + 255) / 256, 256, 0, stream>>>(x, xb, B * I / 4);
  cvt_f32_to_bf16<<<(H * I / 4 + 255) / 256, 256, 0, stream>>>(W_ih, wihb, H * I / 4);
  cvt_f32_to_bf16<<<(H * H / 4 + 255) / 256, 256, 0, stream>>>(W_hh, whhb, H * H / 4);
  init_h<<<(B * H / 4 + 255) / 256, 256, 0, stream>>>(h0, hout, hb0, B * H / 4);

  dim3 grid(H / 128, B / 128);  // (16, 32)
  // ihb = x @ W_ih^T + b_ih + b_hh   (fold both biases once)
  gemm_nt<0><<<grid, 256, 0, stream>>>(xb, wihb, B, H, I, b_ih, b_hh, ihb,
                                       nullptr, nullptr, nullptr, nullptr);

  bf16_t* hb[2] = {hb0, hb1};
  for (int s = 0; s < NUM_STEPS; ++s) {
    gemm_nt<1><<<grid, 256, 0, stream>>>(hb[s & 1], whhb, B, H, H, nullptr,
                                         nullptr, nullptr, ihb, tau, hout,
                                         hb[(s + 1) & 1]);
  }
}